// Round 19
// baseline (170.803 us; speedup 1.0000x reference)
//
#include <hip/hip_runtime.h>
#include <math.h>

#define BB 8
#define SS 2048
#define DD 512
#define HH 8
#define MM (BB*SS)   // 16384

// scan_h chunking
#define CHK 64    // chunks over t
#define CL  32    // stored steps per chunk (CHK*CL == SS)
#define CW  32    // warm-up steps (contraction ~e^-0.87/step; mean e^-28)

// retr fused-EMA chunking
#define RT 64     // stored steps per wave
#define RW 96     // EMA warm-up steps ((1-a)^96 < 5e-4 worst head)

typedef unsigned short u16;
typedef unsigned int   u32;
typedef float f32x4 __attribute__((ext_vector_type(4)));
typedef short s16x8 __attribute__((ext_vector_type(8)));

__device__ __forceinline__ u16 f2bf(float x){
  union { float f; unsigned u; } c; c.f = x;
  unsigned r = c.u + 0x7FFF + ((c.u >> 16) & 1);
  return (u16)(r >> 16);
}
__device__ __forceinline__ float bf2f(u16 x){
  union { unsigned u; float f; } c; c.u = ((unsigned)x) << 16;
  return c.f;
}
__device__ __forceinline__ void gload16(const u16* g, u16* l){
  __builtin_amdgcn_global_load_lds(
      (const __attribute__((address_space(1))) unsigned int*)g,
      (__attribute__((address_space(3))) unsigned int*)l, 16, 0, 0);
}

// ---------------- single fused prep kernel ----------------
// Weights FRAGMENT-MAJOR (R14). Wqk/Wv are LN-g-folded. Wqk q/k interleaved:
// n -> orig row head*64 + (idx>>1) + (idx&1 ? 512 : 0), head=n>>7, idx=n&127.
// c1qk[n]=sum_k g[k]*W[orig(n)][k], c2qk[n]=sum_k beta[k]*W[orig(n)][k];
// c1v/c2v likewise for rows 1024+n.
__global__ void prep_all(const float* __restrict__ ipWr, const float* __restrict__ ipWi,
                         const float* __restrict__ Wqkv,
                         const float* __restrict__ opWr, const float* __restrict__ opWi,
                         const float* __restrict__ ipbr, const float* __restrict__ ipbi,
                         const float* __restrict__ la,
                         const float* __restrict__ lng, const float* __restrict__ lnb,
                         u16* __restrict__ W1, u16* __restrict__ Wqk, u16* __restrict__ Wv,
                         u16* __restrict__ W3,
                         float* __restrict__ tphi2, float* __restrict__ bc,
                         float* __restrict__ alph,
                         float* __restrict__ c1qk, float* __restrict__ c2qk,
                         float* __restrict__ c1v, float* __restrict__ c2v){
  int id = blockIdx.x*256 + threadIdx.x;
  if (id < 524288){
    // W1: N=512, K=1024 (k-interleaved cos/sin), nK=32
    int e = id & 7, lane = (id>>3) & 63, s = (id>>9) & 3;
    int rest = id >> 11, ks = rest & 31, nb2 = rest >> 5;
    int n = (nb2>>1)*128 + (nb2&1)*64 + s*16 + (lane&15);
    int k = ks*32 + (lane>>4)*8 + e;
    int d = k >> 1;
    float v = (k & 1) ? (ipWr[n*512+d] - ipWi[n*512+d])
                      : (ipWr[n*512+d] + ipWi[n*512+d]);
    W1[id] = f2bf(v);
  } else if (id < 1048576){
    // Wqk: N=1024, K=512, nK=16 — q/k interleaved per head, g-folded
    int i = id - 524288;
    int e = i & 7, lane = (i>>3) & 63, s = (i>>9) & 3;
    int rest = i >> 11, ks = rest & 15, nb2 = rest >> 4;   // nb2 0..15
    int n = (nb2>>1)*128 + (nb2&1)*64 + s*16 + (lane&15);  // 0..1023
    int k = ks*32 + (lane>>4)*8 + e;
    int head = n >> 7, idx = n & 127;
    int orig = head*64 + (idx>>1) + ((idx&1) ? 512 : 0);
    Wqk[i] = f2bf(Wqkv[(size_t)orig*512 + k] * lng[k]);
  } else if (id < 1310720){
    // Wv: N=512, K=512, nK=16 — rows 1024..1535 of Wqkv, g-folded
    int i = id - 1048576;
    int e = i & 7, lane = (i>>3) & 63, s = (i>>9) & 3;
    int rest = i >> 11, ks = rest & 15, nb2 = rest >> 4;   // nb2 0..7
    int n = (nb2>>1)*128 + (nb2&1)*64 + s*16 + (lane&15);  // 0..511
    int k = ks*32 + (lane>>4)*8 + e;
    Wv[i] = f2bf(Wqkv[(size_t)(1024+n)*512 + k] * lng[k]);
  } else if (id < 1835008){
    // W3: N=1024, K=512, nK=16
    int i = id - 1310720;
    int e = i & 7, lane = (i>>3) & 63, s = (i>>9) & 3;
    int rest = i >> 11, ks = rest & 15, nb2 = rest >> 4;
    int n = (nb2>>1)*128 + (nb2&1)*64 + s*16 + (lane&15);
    int k = ks*32 + (lane>>4)*8 + e;
    W3[i] = f2bf((n < 512) ? opWr[n*512+k] : opWi[(n-512)*512+k]);
  } else if (id < 1837056){
    int t = id - 1835008;
    const float PHI_F    = 1.61803398874989484820f;
    const float TWO_PI_F = 6.28318530717958647693f;
    tphi2[t] = 2.0f * fmodf((float)t * PHI_F, TWO_PI_F);
  } else if (id < 1837568){
    int t = id - 1837056;
    bc[t] = ipbr[t] + ipbi[t];
  } else if (id < 1837576){
    int t = id - 1837568;
    alph[t] = 1.0f/(1.0f + expf(-la[t]));
  } else if (id < 1838600){
    int n = id - 1837576;          // 0..1023 (permuted qk col)
    int head = n >> 7, idx = n & 127;
    int orig = head*64 + (idx>>1) + ((idx&1) ? 512 : 0);
    const float* wrow = Wqkv + (size_t)orig*512;
    float s1 = 0.f, s2 = 0.f;
    for (int k=0;k<512;k++){
      float wv = wrow[k];
      s1 = fmaf(lng[k], wv, s1);
      s2 = fmaf(lnb[k], wv, s2);
    }
    c1qk[n] = s1; c2qk[n] = s2;
  } else if (id < 1839112){
    int n = id - 1838600;          // 0..511
    const float* wrow = Wqkv + (size_t)(1024+n)*512;
    float s1 = 0.f, s2 = 0.f;
    for (int k=0;k<512;k++){
      float wv = wrow[k];
      s1 = fmaf(lng[k], wv, s1);
      s2 = fmaf(lnb[k], wv, s2);
    }
    c1v[n] = s1; c2v[n] = s2;
  }
}

// ---------------- stats finalize: mu, rstd per row from 8 slice-partials ----------------
__global__ __launch_bounds__(256) void stats_final(const float* __restrict__ Pst,
                                                   float* __restrict__ murs){
  int r = blockIdx.x*256 + threadIdx.x;   // 16384
  const float4* p = (const float4*)(Pst + (size_t)r*16);
  float4 a = p[0], b = p[1], c = p[2], d = p[3];
  float s  = a.x+a.z + b.x+b.z + c.x+c.z + d.x+d.z;
  float s2 = a.y+a.w + b.y+b.w + c.y+c.w + d.y+d.w;
  float mu  = s  * (1.0f/512.0f);
  float var = s2 * (1.0f/512.0f) - mu*mu;
  murs[r*2]   = mu;
  murs[r*2+1] = rsqrtf(var + 1e-5f);
}

// ---------------- phase 1: h-recurrence, chunked restart ----------------
__global__ __launch_bounds__(256) void scan_h(const float* __restrict__ w,
                                              const float* __restrict__ bb,
                                              const float* __restrict__ tphi2,
                                              u32* __restrict__ X32){
  const int e = blockIdx.x*256 + threadIdx.x;   // 0..4095 = B*D
  const int c = blockIdx.y;                     // chunk
  const int b = e >> 9;
  const int d = e & 511;
  const float SQRT2 = 1.41421356237309504880f;
  const float PI_4  = 0.78539816339744830962f;
  const int tstart = c*CL;
  int t0 = tstart - CW; if (t0 < 0) t0 = 0;
  const int nw = tstart - t0;                   // 0 or 32 (multiple of 8)

  const float* wp = w  + ((size_t)b*SS + t0)*DD + d;
  const float* bp = bb + ((size_t)b*SS + t0)*DD + d;
  const float* tp = tphi2 + t0;

  const int U = 8;
  float wv[U], bv[U], wn[U], bn[U];

  float ss = 0.f;   // sin(theta + pi/4); hr+hi = sqrt2*ss
  const int ngw = nw >> 3;
  if (ngw > 0){
    #pragma unroll
    for (int i=0;i<U;i++){ wv[i] = wp[(size_t)i*DD]; bv[i] = bp[(size_t)i*DD]; }
    for (int gg=0; gg<ngw; ++gg){
      if (gg+1 < ngw){
        const float* wnp = wp + (size_t)(gg+1)*U*DD;
        const float* bnp = bp + (size_t)(gg+1)*U*DD;
        #pragma unroll
        for (int i=0;i<U;i++){ wn[i] = wnp[(size_t)i*DD]; bn[i] = bnp[(size_t)i*DD]; }
      }
      #pragma unroll
      for (int i=0;i<U;i++){
        float rwl2 = SQRT2 * __builtin_amdgcn_rcpf(1.0f + fabsf(wv[i]));
        float cw   = fmaf(2.0f, bv[i], tp[gg*U+i]) + PI_4;
        ss = __sinf(fmaf(ss, rwl2, cw));
      }
      #pragma unroll
      for (int i=0;i<U;i++){ wv[i]=wn[i]; bv[i]=bn[i]; }
    }
  }
  float hs = SQRT2 * ss;   // = hr + hi

  const float* wq = wp + (size_t)nw*DD;
  const float* bq = bp + (size_t)nw*DD;
  const float* tq = tp + nw;
  u32* xp = X32 + (size_t)(b*SS + tstart)*512 + d;

  #pragma unroll
  for (int i=0;i<U;i++){ wv[i] = wq[(size_t)i*DD]; bv[i] = bq[(size_t)i*DD]; }
  for (int gg=0; gg<CL/U; ++gg){
    if (gg+1 < CL/U){
      const float* wnp = wq + (size_t)(gg+1)*U*DD;
      const float* bnp = bq + (size_t)(gg+1)*U*DD;
      #pragma unroll
      for (int i=0;i<U;i++){ wn[i] = wnp[(size_t)i*DD]; bn[i] = bnp[(size_t)i*DD]; }
    }
    #pragma unroll
    for (int i=0;i<U;i++){
      float rwl = __builtin_amdgcn_rcpf(1.0f + fabsf(wv[i]));
      float cc  = fmaf(2.0f, bv[i], tq[gg*U+i]);
      float theta = fmaf(hs, rwl, cc);
      float sn = __sinf(theta);
      float cs = __cosf(theta);
      hs = cs + sn;
      xp[(size_t)(gg*U+i)*512] = (u32)f2bf(cs) | ((u32)f2bf(sn) << 16);
    }
    #pragma unroll
    for (int i=0;i<U;i++){ wv[i]=wn[i]; bv[i]=bn[i]; }
  }
}

// ======== shared GEMM pipeline (R14/R18 frozen, copy-pasted per kernel for
// regalloc isolation — rule #19): A via LDS (3-buf rotation, counted vmcnt),
// B direct from L2 via fragment-major coalesced 1KB loads. ========
#define GEMM_PRE(KDIM)                                                   \
  const int K = KDIM, nK = KDIM >> 5;                                    \
  __shared__ __align__(16) u16 As[3][128*32];                            \
  const int tid  = threadIdx.x;                                          \
  const int nwgx = gridDim.x;                                            \
  const int nwg  = nwgx * gridDim.y;                                     \
  const int lin  = blockIdx.y * nwgx + blockIdx.x;                       \
  const int qq   = nwg >> 3;                                             \
  const int logi = (lin & 7) * qq + (lin >> 3);                          \
  const int m0   = (logi / nwgx) * 128;                                  \
  const int n0   = (logi % nwgx) * 128;                                  \
  const int wave = tid >> 6;                                             \
  const int lane = tid & 63;                                             \
  const int wr   = wave >> 1, wc = wave & 1;                             \
  const int l15  = lane & 15;                                            \
  const int g    = lane >> 4;                                            \
  const int rI   = lane >> 2;                                            \
  const int kgs  = (lane & 3) ^ ((lane >> 3) & 3);                       \
  const u16* Asrc0 = A + (size_t)(m0 + wave*32 + rI) * K + kgs*8;        \
  const u16* Asrc1 = A + (size_t)(m0 + wave*32 + 16 + rI) * K + kgs*8;   \
  const int ld0 = (wave*2+0)*512;                                        \
  const int ld1 = (wave*2+1)*512;                                        \
  const u16* Bf = W + ((size_t)((n0 >> 6) + wc) * nK) * 2048 + lane*8;   \
  f32x4 acc[4][4];                                                       \
  _Pragma("unroll")                                                      \
  for (int i=0;i<4;i++)                                                  \
    _Pragma("unroll")                                                    \
    for (int j=0;j<4;j++) acc[i][j] = (f32x4){0.f,0.f,0.f,0.f};          \
  s16x8 b0[4], b1[4];

#define STAGE_A(buf, koff) do {                    \
    gload16(Asrc0 + (koff), &As[buf][ld0]);        \
    gload16(Asrc1 + (koff), &As[buf][ld1]);        \
  } while(0)

#define LOADB(dst, hh) do {                                         \
    _Pragma("unroll")                                               \
    for (int s=0;s<4;s++)                                           \
      dst[s] = *(const s16x8*)(Bf + ((size_t)(hh)*4 + s)*512);      \
  } while(0)

#define PHASE(hh, bcur, bnxt) do {                                       \
    if ((hh)+2 < nK){                                                    \
      int nb = (hh)+2; nb -= (nb/3)*3;                                   \
      STAGE_A(nb, ((hh)+2)*32);                                          \
    }                                                                    \
    if ((hh)+1 < nK) LOADB(bnxt, (hh)+1);                                \
    {                                                                    \
      int rem = nK - 1 - (hh);                                           \
      if      (rem >= 2) asm volatile("s_waitcnt vmcnt(6)" ::: "memory");\
      else if (rem == 1) asm volatile("s_waitcnt vmcnt(4)" ::: "memory");\
      else               asm volatile("s_waitcnt vmcnt(0)" ::: "memory");\
    }                                                                    \
    __builtin_amdgcn_s_barrier();                                        \
    {                                                                    \
      int cb = (hh); cb -= (cb/3)*3;                                     \
      const u16* Ah = &As[cb][0];                                        \
      s16x8 af[4];                                                       \
      _Pragma("unroll")                                                  \
      for (int s=0;s<4;s++){                                             \
        int rA = wr*64 + s*16 + l15;                                     \
        af[s] = *(const s16x8*)&Ah[rA*32 + ((g ^ ((rA>>1)&3))*8)];       \
      }                                                                  \
      __builtin_amdgcn_s_setprio(1);                                     \
      _Pragma("unroll")                                                  \
      for (int mi=0;mi<4;mi++)                                           \
        _Pragma("unroll")                                                \
        for (int ni=0;ni<4;ni++)                                         \
          acc[mi][ni] = __builtin_amdgcn_mfma_f32_16x16x32_bf16(af[mi], bcur[ni], acc[mi][ni], 0, 0, 0); \
      __builtin_amdgcn_s_setprio(0);                                     \
    }                                                                    \
    asm volatile("" ::: "memory");                                       \
    __builtin_amdgcn_s_barrier();                                        \
  } while(0)

#define GEMM_LOOP                                  \
  STAGE_A(0, 0);                                   \
  STAGE_A(1, 32);                                  \
  LOADB(b0, 0);                                    \
  for (int h = 0; h < nK; h += 2){                 \
    PHASE(h,   b0, b1);                            \
    PHASE(h+1, b1, b0);                            \
  }

// ---------------- gemm_y: y = X@W1^T + bc, bf16 out + LN-stats partials ----------------
__global__ __launch_bounds__(256) void gemm_y(const u16* __restrict__ A,
                                              const u16* __restrict__ W,
                                              u16* __restrict__ Y,
                                              const float* __restrict__ bias,
                                              float* __restrict__ Pst){
  GEMM_PRE(1024)
  GEMM_LOOP
  #pragma unroll
  for (int mi=0;mi<4;mi++){
    #pragma unroll
    for (int j=0;j<4;j++){
      int r = m0 + wr*64 + mi*16 + g*4 + j;
      float s1 = 0.f, s2v = 0.f;
      #pragma unroll
      for (int ni=0;ni<4;ni++){
        int col = n0 + wc*64 + ni*16 + l15;
        float vv = acc[mi][ni][j] + bias[col];
        Y[(size_t)r*512 + col] = f2bf(vv);
        s1 += vv; s2v = fmaf(vv, vv, s2v);
      }
      #pragma unroll
      for (int off=1; off<16; off<<=1){
        s1  += __shfl_xor(s1,  off);
        s2v += __shfl_xor(s2v, off);
      }
      if (l15 == 0){
        int slice = (n0 >> 6) + wc;
        Pst[((size_t)r*8 + slice)*2]     = s1;
        Pst[((size_t)r*8 + slice)*2 + 1] = s2v;
      }
    }
  }
}

// ---------------- gemm_qk: qk dots with LN correction, QK[M x 8] f32 ----------------
__global__ __launch_bounds__(256) void gemm_qk(const u16* __restrict__ A,
                                               const u16* __restrict__ W,
                                               const float* __restrict__ murs,
                                               const float* __restrict__ c1,
                                               const float* __restrict__ c2,
                                               float* __restrict__ QK){
  __shared__ float qkp[2][128];
  GEMM_PRE(512)
  GEMM_LOOP
  const int head = n0 >> 7;
  #pragma unroll
  for (int mi=0;mi<4;mi++){
    #pragma unroll
    for (int j=0;j<4;j++){
      int r = m0 + wr*64 + mi*16 + g*4 + j;
      float mu = murs[r*2], rs = murs[r*2+1];
      float p = 0.f;
      #pragma unroll
      for (int ni=0;ni<4;ni++){
        int col = n0 + wc*64 + ni*16 + l15;
        float vv = rs*(acc[mi][ni][j] - mu*c1[col]) + c2[col];
        float pv = __shfl_xor(vv, 1);
        p = fmaf(vv, pv, p);
      }
      p += __shfl_xor(p, 2);
      p += __shfl_xor(p, 4);
      p += __shfl_xor(p, 8);
      if (l15 == 0) qkp[wc][wr*64 + mi*16 + g*4 + j] = p;
    }
  }
  __syncthreads();
  if (tid < 128){
    float s = qkp[0][tid] + qkp[1][tid];
    QK[(size_t)(m0 + tid)*8 + head] = s;
  }
}

// ---------------- gemm_v: v with LN correction, bf16 out ----------------
__global__ __launch_bounds__(256) void gemm_v(const u16* __restrict__ A,
                                              const u16* __restrict__ W,
                                              const float* __restrict__ murs,
                                              const float* __restrict__ c1,
                                              const float* __restrict__ c2,
                                              u16* __restrict__ V){
  GEMM_PRE(512)
  GEMM_LOOP
  #pragma unroll
  for (int mi=0;mi<4;mi++){
    #pragma unroll
    for (int j=0;j<4;j++){
      int r = m0 + wr*64 + mi*16 + g*4 + j;
      float mu = murs[r*2], rs = murs[r*2+1];
      #pragma unroll
      for (int ni=0;ni<4;ni++){
        int col = n0 + wc*64 + ni*16 + l15;
        float vv = rs*(acc[mi][ni][j] - mu*c1[col]) + c2[col];
        V[(size_t)r*512 + col] = f2bf(vv);
      }
    }
  }
}

// ---------------- gemm_out: f32 split C0/C1 stride 512 ----------------
__global__ __launch_bounds__(256) void gemm_out(const u16* __restrict__ A,
                                                const u16* __restrict__ W,
                                                float* __restrict__ C0,
                                                float* __restrict__ C1){
  GEMM_PRE(512)
  GEMM_LOOP
  #pragma unroll
  for (int mi=0;mi<4;mi++){
    #pragma unroll
    for (int j=0;j<4;j++){
      int r = m0 + wr*64 + mi*16 + g*4 + j;
      #pragma unroll
      for (int ni=0;ni<4;ni++){
        int col = n0 + wc*64 + ni*16 + l15;
        float v = acc[mi][ni][j];
        if (col < 512) C0[(size_t)r*512 + col]       = v;
        else           C1[(size_t)r*512 + (col-512)] = v;
      }
    }
  }
}

// ---------------- fused EMA + gate + retr (v dense M x 512; gate from QK) ----------------
__global__ __launch_bounds__(256) void retr_fused(const u16* __restrict__ v,
                                                  const float* __restrict__ QK,
                                                  const float* __restrict__ alph,
                                                  u16* __restrict__ retr){
  const int wid  = blockIdx.x*4 + (threadIdx.x >> 6);   // 0..2047
  const int lane = threadIdx.x & 63;
  const int c = wid & 31;                               // 32 chunks of RT=64
  const int h = (wid >> 5) & 7;
  const int b = wid >> 8;
  const float a  = alph[h];
  const float om = 1.0f - a;
  const int d  = h*64 + lane;
  const int t0 = c*RT;
  int w0 = t0 - RW; if (w0 < 0) w0 = 0;
  const int nw = t0 - w0;                      // multiple of 32

  const u16* vp = v + ((size_t)(b*SS + w0))*512 + d;
  float vs = 0.f;
  {
    const int U = 8;
    float vv[U], vn[U];
    const int ng = nw >> 3;
    if (ng > 0){
      #pragma unroll
      for (int i=0;i<U;i++) vv[i] = bf2f(vp[(size_t)i*512]);
      for (int gg=0; gg<ng; ++gg){
        if (gg+1 < ng){
          const u16* vnp = vp + (size_t)(gg+1)*U*512;
          #pragma unroll
          for (int i=0;i<U;i++) vn[i] = bf2f(vnp[(size_t)i*512]);
        }
        #pragma unroll
        for (int i=0;i<U;i++) vs = fmaf(a, vv[i], om*vs);
        #pragma unroll
        for (int i=0;i<U;i++) vv[i] = vn[i];
      }
    }
  }
  const u16* qp = v + ((size_t)(b*SS + t0))*512 + d;
  const float* gp = QK + ((size_t)(b*SS + t0))*8 + h;
  u16* op = retr + ((size_t)(b*SS + t0))*512 + d;
  #pragma unroll 4
  for (int i=0;i<RT;i++){
    float vv = bf2f(qp[(size_t)i*512]);
    vs = fmaf(a, vv, om*vs);
    float qk = gp[(size_t)i*8];
    float gate = 1.0f/(1.0f + __expf(-qk*0.125f));
    op[(size_t)i*512] = f2bf(gate * vs);
  }
}

extern "C" void kernel_launch(void* const* d_in, const int* in_sizes, int n_in,
                              void* d_out, int out_size, void* d_ws, size_t ws_size,
                              hipStream_t stream) {
  const float* w    = (const float*)d_in[0];
  const float* b    = (const float*)d_in[1];
  const float* ipWr = (const float*)d_in[2];
  const float* ipWi = (const float*)d_in[3];
  const float* ipbr = (const float*)d_in[4];
  const float* ipbi = (const float*)d_in[5];
  const float* lng  = (const float*)d_in[6];
  const float* lnb  = (const float*)d_in[7];
  const float* Wqkv = (const float*)d_in[8];
  const float* la   = (const float*)d_in[9];
  const float* opWr = (const float*)d_in[10];
  const float* opWi = (const float*)d_in[11];
  float* out0 = (float*)d_out;                    // (B,S,D) real part
  float* out1 = out0 + (size_t)MM*DD;             // imag part

  char* base = (char*)d_ws;
  u16*   W1    = (u16*)  (base + 0);              // 512x1024 bf16 fragment-major
  u16*   Wqk   = (u16*)  (base + 1048576);        // 1024x512 frag-major, q/k interleaved, g-folded
  u16*   Wv    = (u16*)  (base + 2097152);        // 512x512 frag-major, g-folded
  u16*   W3    = (u16*)  (base + 2621440);        // 1024x512 frag-major
  float* bc    = (float*)(base + 3670016);        // 512 f32
  float* alph  = (float*)(base + 3672064);        // 8 f32
  float* tphi2 = (float*)(base + 3672128);        // 2048 f32
  float* c1qk  = (float*)(base + 3680384);        // 1024 f32
  float* c2qk  = (float*)(base + 3684480);        // 1024 f32
  float* c1v   = (float*)(base + 3688576);        // 512 f32
  float* c2v   = (float*)(base + 3690624);        // 512 f32
  float* murs  = (float*)(base + 3692672);        // M*2 f32
  float* Pst   = (float*)(base + 3823744);        // M*8*2 f32 (1 MB)
  u32*   X32   = (u32*)  (base + 4872320);        // M*512 u32 (packed bf16 pair)
  u16*   y     = (u16*)  (base + 38426752);       // M*512 bf16
  u16*   v     = (u16*)  (base + 55203968);       // M*512 bf16
  float* QK    = (float*)(base + 71981184);       // M*8 f32
  u16*   retr  = (u16*)X32;                       // alias: X dead after gemm_y

  prep_all<<<7185,256,0,stream>>>(ipWr, ipWi, Wqkv, opWr, opWi, ipbr, ipbi, la,
                                  lng, lnb, W1, Wqk, Wv, W3, tphi2, bc, alph,
                                  c1qk, c2qk, c1v, c2v);

  scan_h<<<dim3(16,CHK),256,0,stream>>>(w, b, tphi2, X32);

  gemm_y<<<dim3(4,128),256,0,stream>>>((const u16*)X32, W1, y, bc, Pst);
  stats_final<<<64,256,0,stream>>>(Pst, murs);

  gemm_qk<<<dim3(8,128),256,0,stream>>>(y, Wqk, murs, c1qk, c2qk, QK);
  gemm_v<<<dim3(4,128),256,0,stream>>>(y, Wv, murs, c1v, c2v, v);

  retr_fused<<<512,256,0,stream>>>(v, QK, alph, retr);

  gemm_out<<<dim3(8,128),256,0,stream>>>(retr, W3, out0, out1);
}

// Round 20
// 153.779 us; speedup vs baseline: 1.1107x; 1.1107x over previous
//
#include <hip/hip_runtime.h>
#include <math.h>

#define BB 8
#define SS 2048
#define DD 512
#define HH 8
#define MM (BB*SS)   // 16384

// scan_h chunking
#define CHK 128   // chunks over t
#define CL  16    // stored steps per chunk (CHK*CL == SS)
#define CW  32    // warm-up steps (contraction ~e^-0.87/step; mean e^-28)

// retr fused-EMA chunking
#define RT 64     // stored steps per wave
#define RW 96     // EMA warm-up steps ((1-a)^96 < 5e-4 worst head)

typedef unsigned short u16;
typedef unsigned int   u32;
typedef float f32x4 __attribute__((ext_vector_type(4)));
typedef short s16x8 __attribute__((ext_vector_type(8)));

__device__ __forceinline__ u16 f2bf(float x){
  union { float f; unsigned u; } c; c.f = x;
  unsigned r = c.u + 0x7FFF + ((c.u >> 16) & 1);
  return (u16)(r >> 16);
}
__device__ __forceinline__ float bf2f(u16 x){
  union { unsigned u; float f; } c; c.u = ((unsigned)x) << 16;
  return c.f;
}
__device__ __forceinline__ void gload16(const u16* g, u16* l){
  __builtin_amdgcn_global_load_lds(
      (const __attribute__((address_space(1))) unsigned int*)g,
      (__attribute__((address_space(3))) unsigned int*)l, 16, 0, 0);
}

// ---------------- single fused prep kernel ----------------
// Weights FRAGMENT-MAJOR: for nb2 = n-64-block, ks = 32-k-step, s = frag:
//   Wfrag[((nb2*nK + ks)*4 + s)*512 + lane*8 + e] = W[n][k],
//   n = (nb2>>1)*128 + (nb2&1)*64 + s*16 + (lane&15),  k = ks*32 + (lane>>4)*8 + e.
// Wqk: cols permuted so head h's q_i (even) / k_i (odd) are adjacent within
// n-block h: n -> orig row head*64 + (idx>>1) + (idx&1 ? 512 : 0), idx=n&127.
__global__ void prep_all(const float* __restrict__ ipWr, const float* __restrict__ ipWi,
                         const float* __restrict__ Wqkv,
                         const float* __restrict__ opWr, const float* __restrict__ opWi,
                         const float* __restrict__ ipbr, const float* __restrict__ ipbi,
                         const float* __restrict__ la,
                         u16* __restrict__ W1, u16* __restrict__ Wqk, u16* __restrict__ Wv,
                         u16* __restrict__ W3,
                         float* __restrict__ tphi2, float* __restrict__ bc,
                         float* __restrict__ alph){
  int id = blockIdx.x*256 + threadIdx.x;
  if (id < 524288){
    // W1: N=512, K=1024 (k-interleaved cos/sin), nK=32
    int e = id & 7, lane = (id>>3) & 63, s = (id>>9) & 3;
    int rest = id >> 11, ks = rest & 31, nb2 = rest >> 5;
    int n = (nb2>>1)*128 + (nb2&1)*64 + s*16 + (lane&15);
    int k = ks*32 + (lane>>4)*8 + e;
    int d = k >> 1;
    float v = (k & 1) ? (ipWr[n*512+d] - ipWi[n*512+d])
                      : (ipWr[n*512+d] + ipWi[n*512+d]);
    W1[id] = f2bf(v);
  } else if (id < 1048576){
    // Wqk: N=1024, K=512, nK=16 — q/k interleaved per head
    int i = id - 524288;
    int e = i & 7, lane = (i>>3) & 63, s = (i>>9) & 3;
    int rest = i >> 11, ks = rest & 15, nb2 = rest >> 4;   // nb2 0..15
    int n = (nb2>>1)*128 + (nb2&1)*64 + s*16 + (lane&15);  // 0..1023
    int k = ks*32 + (lane>>4)*8 + e;
    int head = n >> 7, idx = n & 127;
    int orig = head*64 + (idx>>1) + ((idx&1) ? 512 : 0);
    Wqk[i] = f2bf(Wqkv[(size_t)orig*512 + k]);
  } else if (id < 1310720){
    // Wv: N=512, K=512, nK=16 — rows 1024..1535 of Wqkv
    int i = id - 1048576;
    int e = i & 7, lane = (i>>3) & 63, s = (i>>9) & 3;
    int rest = i >> 11, ks = rest & 15, nb2 = rest >> 4;   // nb2 0..7
    int n = (nb2>>1)*128 + (nb2&1)*64 + s*16 + (lane&15);  // 0..511
    int k = ks*32 + (lane>>4)*8 + e;
    Wv[i] = f2bf(Wqkv[(size_t)(1024+n)*512 + k]);
  } else if (id < 1835008){
    // W3: N=1024, K=512, nK=16
    int i = id - 1310720;
    int e = i & 7, lane = (i>>3) & 63, s = (i>>9) & 3;
    int rest = i >> 11, ks = rest & 15, nb2 = rest >> 4;
    int n = (nb2>>1)*128 + (nb2&1)*64 + s*16 + (lane&15);
    int k = ks*32 + (lane>>4)*8 + e;
    W3[i] = f2bf((n < 512) ? opWr[n*512+k] : opWi[(n-512)*512+k]);
  } else if (id < 1837056){
    int t = id - 1835008;
    const float PHI_F    = 1.61803398874989484820f;
    const float TWO_PI_F = 6.28318530717958647693f;
    tphi2[t] = 2.0f * fmodf((float)t * PHI_F, TWO_PI_F);
  } else if (id < 1837568){
    int t = id - 1837056;
    bc[t] = ipbr[t] + ipbi[t];
  } else if (id < 1837576){
    int t = id - 1837568;
    alph[t] = 1.0f/(1.0f + expf(-la[t]));
  }
}

// ---------------- phase 1: h-recurrence, chunked restart (R14 form) ----------------
__global__ __launch_bounds__(256) void scan_h(const float* __restrict__ w,
                                              const float* __restrict__ bb,
                                              const float* __restrict__ tphi2,
                                              u32* __restrict__ X32){
  const int e = blockIdx.x*256 + threadIdx.x;   // 0..4095 = B*D
  const int c = blockIdx.y;                     // chunk
  const int b = e >> 9;
  const int d = e & 511;
  const float SQRT2 = 1.41421356237309504880f;
  const float PI_4  = 0.78539816339744830962f;
  const int tstart = c*CL;
  int t0 = tstart - CW; if (t0 < 0) t0 = 0;
  const int nw = tstart - t0;                   // 0,16,32 (multiple of 8)

  const float* wp = w  + ((size_t)b*SS + t0)*DD + d;
  const float* bp = bb + ((size_t)b*SS + t0)*DD + d;
  const float* tp = tphi2 + t0;

  const int U = 8;
  float wv[U], bv[U], wn[U], bn[U];

  float ss = 0.f;   // sin(theta + pi/4); hr+hi = sqrt2*ss
  const int ngw = nw >> 3;
  if (ngw > 0){
    #pragma unroll
    for (int i=0;i<U;i++){ wv[i] = wp[(size_t)i*DD]; bv[i] = bp[(size_t)i*DD]; }
    for (int gg=0; gg<ngw; ++gg){
      if (gg+1 < ngw){
        const float* wnp = wp + (size_t)(gg+1)*U*DD;
        const float* bnp = bp + (size_t)(gg+1)*U*DD;
        #pragma unroll
        for (int i=0;i<U;i++){ wn[i] = wnp[(size_t)i*DD]; bn[i] = bnp[(size_t)i*DD]; }
      }
      #pragma unroll
      for (int i=0;i<U;i++){
        float rwl2 = SQRT2 * __builtin_amdgcn_rcpf(1.0f + fabsf(wv[i]));
        float cw   = fmaf(2.0f, bv[i], tp[gg*U+i]) + PI_4;
        ss = __sinf(fmaf(ss, rwl2, cw));
      }
      #pragma unroll
      for (int i=0;i<U;i++){ wv[i]=wn[i]; bv[i]=bn[i]; }
    }
  }
  float hs = SQRT2 * ss;   // = hr + hi

  const float* wq = wp + (size_t)nw*DD;
  const float* bq = bp + (size_t)nw*DD;
  const float* tq = tp + nw;
  u32* xp = X32 + (size_t)(b*SS + tstart)*512 + d;

  #pragma unroll
  for (int i=0;i<U;i++){ wv[i] = wq[(size_t)i*DD]; bv[i] = bq[(size_t)i*DD]; }
  for (int gg=0; gg<CL/U; ++gg){
    if (gg+1 < CL/U){
      const float* wnp = wq + (size_t)(gg+1)*U*DD;
      const float* bnp = bq + (size_t)(gg+1)*U*DD;
      #pragma unroll
      for (int i=0;i<U;i++){ wn[i] = wnp[(size_t)i*DD]; bn[i] = bnp[(size_t)i*DD]; }
    }
    #pragma unroll
    for (int i=0;i<U;i++){
      float rwl = __builtin_amdgcn_rcpf(1.0f + fabsf(wv[i]));
      float cc  = fmaf(2.0f, bv[i], tq[gg*U+i]);
      float theta = fmaf(hs, rwl, cc);
      float sn = __sinf(theta);
      float cs = __cosf(theta);
      hs = cs + sn;
      xp[(size_t)(gg*U+i)*512] = (u32)f2bf(cs) | ((u32)f2bf(sn) << 16);
    }
    #pragma unroll
    for (int i=0;i<U;i++){ wv[i]=wn[i]; bv[i]=bn[i]; }
  }
}

// ---------------- bf16 MFMA GEMM: C[M x N] = A[M x K] @ W[N x K]^T ----------------
// R14 structure (frozen): A via LDS (3-buffer rotation, counted vmcnt),
// B direct from L2 via fragment-major coalesced 1KB loads, double-buffered regs.
// EPI: 1 = f32 split C0/C1 stride 512; 2 = bf16->C2 stride N;
//      3 = bf16->C2 stride N with f32 bias[col] added before rounding.
template<int TAG, int EPI>
__global__ __launch_bounds__(256) void gemm_bf16(const u16* __restrict__ A,
                                                 const u16* __restrict__ W,
                                                 float* __restrict__ C0,
                                                 float* __restrict__ C1,
                                                 u16* __restrict__ C2,
                                                 const float* __restrict__ bias,
                                                 int N, int K){
  __shared__ __align__(16) u16 As[3][128*32];   // 8KB per buffer
  const int tid  = threadIdx.x;
  const int nwgx = gridDim.x;
  const int nwg  = nwgx * gridDim.y;
  const int lin  = blockIdx.y * nwgx + blockIdx.x;
  const int qq   = nwg >> 3;
  const int logi = (lin & 7) * qq + (lin >> 3);
  const int m0   = (logi / nwgx) * 128;
  const int n0   = (logi % nwgx) * 128;

  const int wave = tid >> 6;
  const int lane = tid & 63;
  const int wr   = wave >> 1, wc = wave & 1;
  const int l15  = lane & 15;
  const int g    = lane >> 4;

  const int rI   = lane >> 2;
  const int kgs  = (lane & 3) ^ ((lane >> 3) & 3);
  const int row0 = wave*32 + rI;
  const int row1 = wave*32 + 16 + rI;
  const u16* Asrc0 = A + (size_t)(m0 + row0) * K + kgs*8;
  const u16* Asrc1 = A + (size_t)(m0 + row1) * K + kgs*8;
  const int ld0 = (wave*2+0)*512;
  const int ld1 = (wave*2+1)*512;

  const int nK = K >> 5;
  const u16* Bf = W + ((size_t)((n0 >> 6) + wc) * nK) * 2048 + lane*8;

  f32x4 acc[4][4];
  #pragma unroll
  for (int i=0;i<4;i++)
    #pragma unroll
    for (int j=0;j<4;j++) acc[i][j] = (f32x4){0.f,0.f,0.f,0.f};

  s16x8 b0[4], b1[4];

#define STAGE_A(buf, koff) do {                    \
    gload16(Asrc0 + (koff), &As[buf][ld0]);        \
    gload16(Asrc1 + (koff), &As[buf][ld1]);        \
  } while(0)

#define LOADB(dst, hh) do {                                         \
    _Pragma("unroll")                                               \
    for (int s=0;s<4;s++)                                           \
      dst[s] = *(const s16x8*)(Bf + ((size_t)(hh)*4 + s)*512);      \
  } while(0)

#define PHASE(hh, bcur, bnxt) do {                                       \
    if ((hh)+2 < nK){                                                    \
      int nb = (hh)+2; nb -= (nb/3)*3;                                   \
      STAGE_A(nb, ((hh)+2)*32);                                          \
    }                                                                    \
    if ((hh)+1 < nK) LOADB(bnxt, (hh)+1);                                \
    {                                                                    \
      int rem = nK - 1 - (hh);                                           \
      if      (rem >= 2) asm volatile("s_waitcnt vmcnt(6)" ::: "memory");\
      else if (rem == 1) asm volatile("s_waitcnt vmcnt(4)" ::: "memory");\
      else               asm volatile("s_waitcnt vmcnt(0)" ::: "memory");\
    }                                                                    \
    __builtin_amdgcn_s_barrier();                                        \
    {                                                                    \
      int cb = (hh); cb -= (cb/3)*3;                                     \
      const u16* Ah = &As[cb][0];                                        \
      s16x8 af[4];                                                       \
      _Pragma("unroll")                                                  \
      for (int s=0;s<4;s++){                                             \
        int rA = wr*64 + s*16 + l15;                                     \
        af[s] = *(const s16x8*)&Ah[rA*32 + ((g ^ ((rA>>1)&3))*8)];       \
      }                                                                  \
      __builtin_amdgcn_s_setprio(1);                                     \
      _Pragma("unroll")                                                  \
      for (int mi=0;mi<4;mi++)                                           \
        _Pragma("unroll")                                                \
        for (int ni=0;ni<4;ni++)                                         \
          acc[mi][ni] = __builtin_amdgcn_mfma_f32_16x16x32_bf16(af[mi], bcur[ni], acc[mi][ni], 0, 0, 0); \
      __builtin_amdgcn_s_setprio(0);                                     \
    }                                                                    \
    asm volatile("" ::: "memory");                                       \
    __builtin_amdgcn_s_barrier();                                        \
  } while(0)

  STAGE_A(0, 0);
  STAGE_A(1, 32);
  LOADB(b0, 0);

  for (int h = 0; h < nK; h += 2){
    PHASE(h,   b0, b1);
    PHASE(h+1, b1, b0);
  }

#undef STAGE_A
#undef LOADB
#undef PHASE

  #pragma unroll
  for (int mi=0;mi<4;mi++){
    #pragma unroll
    for (int j=0;j<4;j++){
      int r = m0 + wr*64 + mi*16 + g*4 + j;
      #pragma unroll
      for (int ni=0;ni<4;ni++){
        int col = n0 + wc*64 + ni*16 + l15;
        float v = acc[mi][ni][j];
        if (EPI == 1){
          if (col < 512) C0[(size_t)r*512 + col]       = v;
          else           C1[(size_t)r*512 + (col-512)] = v;
        } else if (EPI == 2){
          C2[(size_t)r*N + col] = f2bf(v);
        } else {
          C2[(size_t)r*N + col] = f2bf(v + bias[col]);
        }
      }
    }
  }
}

// ---------------- gemm_qk: A[M x 512] @ Wqk[1024 x 512]^T, emits ONLY qk dots ----------------
// Same pipeline as gemm_bf16 (separate function: regalloc isolation).
// n-block = head; cols 2i/2i+1 = q_i/k_i. Epilogue: per-row sum of even*odd
// pairs via shfl_xor(1) + l15 xor-reduce (even lanes only — each pair counted
// ONCE) + 2-wave LDS combine -> QK[M x 8] f32.
__global__ __launch_bounds__(256) void gemm_qk(const u16* __restrict__ A,
                                               const u16* __restrict__ W,
                                               float* __restrict__ QK){
  const int K = 512, nK = 16;
  __shared__ __align__(16) u16 As[3][128*32];
  __shared__ float qkp[2][128];
  const int tid  = threadIdx.x;
  const int nwgx = gridDim.x;             // 8
  const int nwg  = nwgx * gridDim.y;
  const int lin  = blockIdx.y * nwgx + blockIdx.x;
  const int qq   = nwg >> 3;
  const int logi = (lin & 7) * qq + (lin >> 3);
  const int m0   = (logi / nwgx) * 128;
  const int n0   = (logi % nwgx) * 128;
  const int head = n0 >> 7;

  const int wave = tid >> 6;
  const int lane = tid & 63;
  const int wr   = wave >> 1, wc = wave & 1;
  const int l15  = lane & 15;
  const int g    = lane >> 4;

  const int rI   = lane >> 2;
  const int kgs  = (lane & 3) ^ ((lane >> 3) & 3);
  const u16* Asrc0 = A + (size_t)(m0 + wave*32 + rI) * K + kgs*8;
  const u16* Asrc1 = A + (size_t)(m0 + wave*32 + 16 + rI) * K + kgs*8;
  const int ld0 = (wave*2+0)*512;
  const int ld1 = (wave*2+1)*512;
  const u16* Bf = W + ((size_t)((n0 >> 6) + wc) * nK) * 2048 + lane*8;

  f32x4 acc[4][4];
  #pragma unroll
  for (int i=0;i<4;i++)
    #pragma unroll
    for (int j=0;j<4;j++) acc[i][j] = (f32x4){0.f,0.f,0.f,0.f};

  s16x8 b0[4], b1[4];

#define QSTAGE_A(buf, koff) do {                   \
    gload16(Asrc0 + (koff), &As[buf][ld0]);        \
    gload16(Asrc1 + (koff), &As[buf][ld1]);        \
  } while(0)

#define QLOADB(dst, hh) do {                                        \
    _Pragma("unroll")                                               \
    for (int s=0;s<4;s++)                                           \
      dst[s] = *(const s16x8*)(Bf + ((size_t)(hh)*4 + s)*512);      \
  } while(0)

#define QPHASE(hh, bcur, bnxt) do {                                      \
    if ((hh)+2 < nK){                                                    \
      int nb = (hh)+2; nb -= (nb/3)*3;                                   \
      QSTAGE_A(nb, ((hh)+2)*32);                                         \
    }                                                                    \
    if ((hh)+1 < nK) QLOADB(bnxt, (hh)+1);                               \
    {                                                                    \
      int rem = nK - 1 - (hh);                                           \
      if      (rem >= 2) asm volatile("s_waitcnt vmcnt(6)" ::: "memory");\
      else if (rem == 1) asm volatile("s_waitcnt vmcnt(4)" ::: "memory");\
      else               asm volatile("s_waitcnt vmcnt(0)" ::: "memory");\
    }                                                                    \
    __builtin_amdgcn_s_barrier();                                        \
    {                                                                    \
      int cb = (hh); cb -= (cb/3)*3;                                     \
      const u16* Ah = &As[cb][0];                                        \
      s16x8 af[4];                                                       \
      _Pragma("unroll")                                                  \
      for (int s=0;s<4;s++){                                             \
        int rA = wr*64 + s*16 + l15;                                     \
        af[s] = *(const s16x8*)&Ah[rA*32 + ((g ^ ((rA>>1)&3))*8)];       \
      }                                                                  \
      __builtin_amdgcn_s_setprio(1);                                     \
      _Pragma("unroll")                                                  \
      for (int mi=0;mi<4;mi++)                                           \
        _Pragma("unroll")                                                \
        for (int ni=0;ni<4;ni++)                                         \
          acc[mi][ni] = __builtin_amdgcn_mfma_f32_16x16x32_bf16(af[mi], bcur[ni], acc[mi][ni], 0, 0, 0); \
      __builtin_amdgcn_s_setprio(0);                                     \
    }                                                                    \
    asm volatile("" ::: "memory");                                       \
    __builtin_amdgcn_s_barrier();                                        \
  } while(0)

  QSTAGE_A(0, 0);
  QSTAGE_A(1, 32);
  QLOADB(b0, 0);

  for (int h = 0; h < nK; h += 2){
    QPHASE(h,   b0, b1);
    QPHASE(h+1, b1, b0);
  }

#undef QSTAGE_A
#undef QLOADB
#undef QPHASE

  // epilogue: per-row q.k pair sums; cols 2i (q) / 2i+1 (k) adjacent in l15.
  #pragma unroll
  for (int mi=0;mi<4;mi++){
    #pragma unroll
    for (int j=0;j<4;j++){
      float p = 0.f;
      #pragma unroll
      for (int ni=0;ni<4;ni++){
        float av = acc[mi][ni][j];
        float pv = __shfl_xor(av, 1);
        p = fmaf(av, pv, p);
      }
      p += __shfl_xor(p, 2);
      p += __shfl_xor(p, 4);
      p += __shfl_xor(p, 8);
      if (l15 == 0) qkp[wc][wr*64 + mi*16 + g*4 + j] = p;
    }
  }
  __syncthreads();
  if (tid < 128){
    float s = qkp[0][tid] + qkp[1][tid];   // each pair counted once per wave half
    QK[(size_t)(m0 + tid)*8 + head] = s;
  }
}

// ---------------- LayerNorm: xc = LN(y)*g + b  (bias pre-added in gemm1) ----------------
__global__ __launch_bounds__(256) void ln_kernel(const u16* __restrict__ y,
                                                 const float* __restrict__ g,
                                                 const float* __restrict__ bb,
                                                 u16* __restrict__ xc){
  const int row  = blockIdx.x*4 + (threadIdx.x >> 6);
  const int lane = threadIdx.x & 63;
  s16x8 v = *(const s16x8*)(y + (size_t)row*512 + lane*8);
  float f[8];
  #pragma unroll
  for (int i=0;i<8;i++) f[i] = bf2f((u16)v[i]);
  float s = 0.f, s2 = 0.f;
  #pragma unroll
  for (int i=0;i<8;i++){ s += f[i]; s2 = fmaf(f[i], f[i], s2); }
  #pragma unroll
  for (int off=32; off>0; off>>=1){ s += __shfl_xor(s, off); s2 += __shfl_xor(s2, off); }
  float mean = s * (1.0f/512.0f);
  float var  = s2 * (1.0f/512.0f) - mean*mean;
  float rstd = rsqrtf(var + 1e-5f);
  float4 g0 = ((const float4*)g)[lane*2],  g1 = ((const float4*)g)[lane*2+1];
  float4 b0 = ((const float4*)bb)[lane*2], b1 = ((const float4*)bb)[lane*2+1];
  s16x8 o;
  o[0] = (short)f2bf((f[0]-mean)*rstd*g0.x + b0.x);
  o[1] = (short)f2bf((f[1]-mean)*rstd*g0.y + b0.y);
  o[2] = (short)f2bf((f[2]-mean)*rstd*g0.z + b0.z);
  o[3] = (short)f2bf((f[3]-mean)*rstd*g0.w + b0.w);
  o[4] = (short)f2bf((f[4]-mean)*rstd*g1.x + b1.x);
  o[5] = (short)f2bf((f[5]-mean)*rstd*g1.y + b1.y);
  o[6] = (short)f2bf((f[6]-mean)*rstd*g1.z + b1.z);
  o[7] = (short)f2bf((f[7]-mean)*rstd*g1.w + b1.w);
  *(s16x8*)(xc + (size_t)row*512 + lane*8) = o;
}

// ---------------- fused EMA + gate + retr (v dense M x 512; gate from QK) ----------------
__global__ __launch_bounds__(256) void retr_fused(const u16* __restrict__ v,
                                                  const float* __restrict__ QK,
                                                  const float* __restrict__ alph,
                                                  u16* __restrict__ retr){
  const int wid  = blockIdx.x*4 + (threadIdx.x >> 6);   // 0..2047
  const int lane = threadIdx.x & 63;
  const int c = wid & 31;                               // 32 chunks of RT=64
  const int h = (wid >> 5) & 7;
  const int b = wid >> 8;
  const float a  = alph[h];
  const float om = 1.0f - a;
  const int d  = h*64 + lane;
  const int t0 = c*RT;
  int w0 = t0 - RW; if (w0 < 0) w0 = 0;
  const int nw = t0 - w0;                      // multiple of 32

  const u16* vp = v + ((size_t)(b*SS + w0))*512 + d;
  float vs = 0.f;
  {
    const int U = 8;
    float vv[U], vn[U];
    const int ng = nw >> 3;
    if (ng > 0){
      #pragma unroll
      for (int i=0;i<U;i++) vv[i] = bf2f(vp[(size_t)i*512]);
      for (int gg=0; gg<ng; ++gg){
        if (gg+1 < ng){
          const u16* vnp = vp + (size_t)(gg+1)*U*512;
          #pragma unroll
          for (int i=0;i<U;i++) vn[i] = bf2f(vnp[(size_t)i*512]);
        }
        #pragma unroll
        for (int i=0;i<U;i++) vs = fmaf(a, vv[i], om*vs);
        #pragma unroll
        for (int i=0;i<U;i++) vv[i] = vn[i];
      }
    }
  }
  const u16* qp = v + ((size_t)(b*SS + t0))*512 + d;
  const float* gp = QK + ((size_t)(b*SS + t0))*8 + h;
  u16* op = retr + ((size_t)(b*SS + t0))*512 + d;
  #pragma unroll 4
  for (int i=0;i<RT;i++){
    float vv = bf2f(qp[(size_t)i*512]);
    vs = fmaf(a, vv, om*vs);
    float qk = gp[(size_t)i*8];
    float gate = 1.0f/(1.0f + __expf(-qk*0.125f));
    op[(size_t)i*512] = f2bf(gate * vs);
  }
}

extern "C" void kernel_launch(void* const* d_in, const int* in_sizes, int n_in,
                              void* d_out, int out_size, void* d_ws, size_t ws_size,
                              hipStream_t stream) {
  const float* w    = (const float*)d_in[0];
  const float* b    = (const float*)d_in[1];
  const float* ipWr = (const float*)d_in[2];
  const float* ipWi = (const float*)d_in[3];
  const float* ipbr = (const float*)d_in[4];
  const float* ipbi = (const float*)d_in[5];
  const float* lng  = (const float*)d_in[6];
  const float* lnb  = (const float*)d_in[7];
  const float* Wqkv = (const float*)d_in[8];
  const float* la   = (const float*)d_in[9];
  const float* opWr = (const float*)d_in[10];
  const float* opWi = (const float*)d_in[11];
  float* out0 = (float*)d_out;                    // (B,S,D) real part
  float* out1 = out0 + (size_t)MM*DD;             // imag part

  char* base = (char*)d_ws;
  u16*   W1    = (u16*)  (base + 0);              // 512x1024 bf16 fragment-major
  u16*   Wqk   = (u16*)  (base + 1048576);        // 1024x512 bf16 frag-major, q/k interleaved
  u16*   Wv    = (u16*)  (base + 2097152);        // 512x512 bf16 fragment-major
  u16*   W3    = (u16*)  (base + 2621440);        // 1024x512 bf16 fragment-major
  float* bc    = (float*)(base + 3670016);        // 512 f32
  float* alph  = (float*)(base + 3672064);        // 8 f32
  float* tphi2 = (float*)(base + 3672128);        // 2048 f32
  u32*   X32   = (u32*)  (base + 3680384);        // M*512 u32 (packed bf16 pair)
  u16*   y     = (u16*)  (base + 37234816);       // M*512 bf16
  u16*   xc    = (u16*)  (base + 54012032);       // M*512 bf16
  u16*   v     = (u16*)  (base + 70789248);       // M*512 bf16
  float* QK    = (float*)(base + 87566464);       // M*8 f32
  u16*   retr  = (u16*)X32;                       // alias: X dead after GEMM1

  prep_all<<<7179,256,0,stream>>>(ipWr, ipWi, Wqkv, opWr, opWi, ipbr, ipbi, la,
                                  W1, Wqk, Wv, W3, tphi2, bc, alph);

  scan_h<<<dim3(16,CHK),256,0,stream>>>(w, b, tphi2, X32);

  gemm_bf16<1,3><<<dim3(4,128),256,0,stream>>>((const u16*)X32, W1, nullptr, nullptr, y, bc, 512, 1024);
  ln_kernel<<<4096,256,0,stream>>>(y, lng, lnb, xc);

  gemm_qk<<<dim3(8,128),256,0,stream>>>(xc, Wqk, QK);
  gemm_bf16<2,2><<<dim3(4,128),256,0,stream>>>(xc, Wv, nullptr, nullptr, v, nullptr, 512, 512);

  retr_fused<<<512,256,0,stream>>>(v, QK, alph, retr);

  gemm_bf16<3,1><<<dim3(8,128),256,0,stream>>>(retr, W3, out0, out1, nullptr, nullptr, 1024, 512);
}